// Round 19
// baseline (873.868 us; speedup 1.0000x reference)
//
#include <hip/hip_runtime.h>
#include <math.h>

namespace {

constexpr int Hn = 50;    // hidden size
constexpr int Bn = 2048;  // batch
constexpr int Tn = 512;   // sequence length
constexpr int SW = 72;    // plane row stride in shorts (144 B)

constexpr float KS1f = -1.44269504088896340736f;  // -log2(e)   (sigmoid rows i,f,o)
constexpr float KS2f = -2.88539008177792681472f;  // -2*log2(e) (tanh row g, and tanh(c))

typedef short short8 __attribute__((ext_vector_type(8)));
typedef float f32x4 __attribute__((ext_vector_type(4)));

__device__ __forceinline__ unsigned bcu(float f) { return __builtin_bit_cast(unsigned, f); }
__device__ __forceinline__ float bcf(unsigned u) { return __builtin_bit_cast(float, u); }
__device__ __forceinline__ float rcpa(float x) { return __builtin_amdgcn_rcpf(x); }

__device__ __forceinline__ float fexp2(float x) {
#if defined(__has_builtin)
#if __has_builtin(__builtin_amdgcn_exp2f)
  return __builtin_amdgcn_exp2f(x);
#else
  return exp2f(x);
#endif
#else
  return exp2f(x);
#endif
}

__device__ __forceinline__ void wsplit(short* ph, short* pl, float v) {
  const unsigned u = bcu(v);
  *ph = (short)(u >> 16);
  *pl = (short)(bcu(v - bcf(u & 0xFFFF0000u)) >> 16);
}

#define MF(a, b, c) __builtin_amdgcn_mfma_f32_16x16x32_bf16(a, b, c, 0, 0, 0)

// inline-asm MFMA, AGPR A-operand + AGPR accumulator, with EXPLICIT hazard
// fences (R25 failed: hazard recognizer can't see inside INLINEASM; races
// gave absmax 2.9e-3). Leading s_nop 2 covers VALU-write -> MFMA SrcB/SrcC
// wait states; MFMA_AA_END's trailing 19 waits cover MFMA AGPR-write ->
// v_accvgpr_read (CUP) even if the scheduler hoists the reads.
#define MFMA_AA(ACC, FA, UB)                                                 \
  asm("s_nop 2\n\t"                                                          \
      "v_mfma_f32_16x16x32_bf16 %0, %1, %2, %0"                              \
      : "+a"(ACC)                                                            \
      : "a"(FA), "v"(UB))

#define MFMA_AA_END(ACC, FA, UB)                                             \
  asm("s_nop 2\n\t"                                                          \
      "v_mfma_f32_16x16x32_bf16 %0, %1, %2, %0\n\t"                          \
      "s_nop 7\n\t"                                                          \
      "s_nop 7\n\t"                                                          \
      "s_nop 2"                                                              \
      : "+a"(ACC)                                                            \
      : "a"(FA), "v"(UB))

// ============================================================================
// FUSED 3-layer LSTM + FC, systolic in time. R26 = R25 (J2 weight frags in
// AGPRs via asm MFMA; kills 64 loop-invariant ds_read_b128/iter + 64KB LDS)
// with the MFMA hazard fences the hazard recognizer can't insert around
// inline asm. Base: R23 (767us best; R24 stagger regressed -> LDS binding).
// Kept from R23: aux waves (L1-w1 carries L2 tile 12, L1-w2 carries L3 tile
// 12 via s_f4j3); bias-via-k-slot (p1 1.0@51, p2 1.0@50; acc init 0); T5
// setprio; tile-major triplets (R13: same-acc MFMA chains are free);
// exp2-prescaled weights -> gates rcp(1+exp2(z')), tanh=2*rcp(1+e)-1;
// 3-term split-bf16; planes K=64: P1=[x,h1(1..50),1@51], P2=[h2,1@50],
// P3=[h3]; ONE barrier/iter.
// Gates: absmax EXACTLY 2.4414e-4 (else AGPR door closes; revert to R23);
// WRITE_SIZE ~8KB; VGPR ~76; LDS ~45KB.
// ============================================================================

#define LW(FI)                                                               \
  short8 FH##FI = {0, 0, 0, 0, 0, 0, 0, 0};                                  \
  short8 FL##FI = {0, 0, 0, 0, 0, 0, 0, 0};                                  \
  {                                                                          \
    const int tile_ =                                                        \
        ((FI) >= 16) ? ((L == 0 || wl != 0) ? 13 : 12)                       \
        : ((FI) >= 8) ? ((L == 0) ? 13 : (wl + 8))                           \
        : (L == 0)    ? (wl + 4 * ((FI) >> 1))                               \
                      : (wl + 4 * ((FI) >> 2));                              \
    const int chunk_ = ((FI) >= 8) ? ((FI)&3)                                \
                       : (L == 0)  ? ((FI)&1)                                \
                                   : ((FI)&3);                               \
    const int cb_ = 4 * tile_ + (nl >> 2);                                   \
    if (tile_ < 13 && cb_ < Hn) {                                            \
      const int row_ = (nl & 3) * Hn + cb_;                                  \
      const float sc_ = ((nl & 3) == 2) ? KS2f : KS1f;                       \
      _Pragma("unroll") for (int jj = 0; jj < 8; ++jj) {                     \
        const int k_ = 32 * chunk_ + quad * 8 + jj;                          \
        float wv = 0.f;                                                      \
        if (L == 0) {                                                        \
          if (k_ == 0) wv = wihL[row_];                                      \
          else if (k_ <= Hn) wv = whhL[row_ * Hn + k_ - 1];                  \
          else if (k_ == 51) wv = biasL[row_];                               \
        } else if (L == 1) {                                                 \
          if (k_ >= 1 && k_ <= Hn) wv = wihL[row_ * Hn + k_ - 1];            \
          else if (k_ == 51) wv = biasL[row_];                               \
          else if (k_ >= 64 && k_ < 64 + Hn) wv = whhL[row_ * Hn + k_ - 64]; \
        } else {                                                             \
          if (k_ < Hn) wv = wihL[row_ * Hn + k_];                            \
          else if (k_ == Hn) wv = biasL[row_];                               \
          else if (k_ >= 64 && k_ < 64 + Hn) wv = whhL[row_ * Hn + k_ - 64]; \
        }                                                                    \
        wv *= sc_;                                                           \
        const unsigned uu = bcu(wv);                                         \
        FH##FI[jj] = (short)(uu >> 16);                                      \
        FL##FI[jj] = (short)(bcu(wv - bcf(uu & 0xFFFF0000u)) >> 16);         \
      }                                                                      \
    }                                                                        \
  }

#define BINIT(J)                                                             \
  const int tile##J = wl + 4 * (J);                                          \
  const int tv##J = tile##J < 13;                                            \
  const int cell##J = 4 * tile##J + quad;                                    \
  float cs##J = 0.f, hl##J = 0.f;

// tile-major triplet (R13-proven: dependent same-acc MFMAs are free)
#define MTM(J, FI)                                                           \
  if (tv##J) {                                                               \
    ac##J = MF(FH##FI, uh_, ac##J);                                          \
    ac##J = MF(FL##FI, uh_, ac##J);                                          \
    ac##J = MF(FH##FI, ul_, ac##J);                                          \
  }

// J2 (tiles 8..11): fragments in AGPR, asm MFMA, zero LDS
#define MTMS2(CI)                                                            \
  {                                                                          \
    MFMA_AA(ac2, aj2h##CI, uh_);                                             \
    MFMA_AA(ac2, aj2l##CI, uh_);                                             \
    MFMA_AA(ac2, aj2h##CI, ul_);                                             \
  }

// last chunk of the iteration: trailing hazard fence before CUP reads
#define MTMS2E(CI)                                                           \
  {                                                                          \
    MFMA_AA(ac2, aj2h##CI, uh_);                                             \
    MFMA_AA(ac2, aj2l##CI, uh_);                                             \
    MFMA_AA_END(ac2, aj2h##CI, ul_);                                         \
  }

#define MCH_L1(LC, F0, F1, F2, F3)                                           \
  {                                                                          \
    const short8 uh_ = *(const short8*)&p1h[rb][nl][32 * (LC) + quad * 8];   \
    const short8 ul_ = *(const short8*)&p1l[rb][nl][32 * (LC) + quad * 8];   \
    MTM(0, F0) MTM(1, F1) MTM(2, F2) MTM(3, F3)                              \
  }

// L2/L3 chunk: J0,J1 reg + J2 AGPR-asm (tile 12 lives on aux L1 waves)
#define MCH_L23(PH, PL, LC, CI, F0, F1)                                      \
  {                                                                          \
    const short8 uh_ = *(const short8*)&PH[rb][nl][32 * (LC) + quad * 8];    \
    const short8 ul_ = *(const short8*)&PL[rb][nl][32 * (LC) + quad * 8];    \
    MTM(0, F0) MTM(1, F1) MTMS2(CI)                                          \
  }

// last-chunk variant (CI=3): hazard-fenced J2 tail
#define MCH_L23E(PH, PL, LC, CI, F0, F1)                                     \
  {                                                                          \
    const short8 uh_ = *(const short8*)&PH[rb][nl][32 * (LC) + quad * 8];    \
    const short8 ul_ = *(const short8*)&PL[rb][nl][32 * (LC) + quad * 8];    \
    MTM(0, F0) MTM(1, F1) MTMS2E(CI)                                         \
  }

// aux chunk (L1-w1 = L2 tile 12 via s_f4j3[0]; L1-w2 = L3 tile 12 via [1])
#define AUX_MCH(AZ, PH, PL, LC, CI)                                          \
  {                                                                          \
    const short8 uh_ = *(const short8*)&PH[rb][nl][32 * (LC) + quad * 8];    \
    const short8 ul_ = *(const short8*)&PL[rb][nl][32 * (LC) + quad * 8];    \
    const short8 fh_ = s_f4j3[AZ][CI][0][lane];                              \
    const short8 fl_ = s_f4j3[AZ][CI][1][lane];                              \
    acA = MF(fh_, uh_, acA);                                                 \
    acA = MF(fl_, uh_, acA);                                                 \
    acA = MF(fh_, ul_, acA);                                                 \
  }

// cell update for tile J; SINGLE h write into plane (PH,PL) at k = KO+cell
#define CUP(J, PH, PL, KO)                                                   \
  if (tv##J) {                                                               \
    const float I_ = rcpa(1.0f + fexp2(ac##J[0]));                           \
    const float F_ = rcpa(1.0f + fexp2(ac##J[1]));                           \
    const float G_ = fmaf(2.0f, rcpa(1.0f + fexp2(ac##J[2])), -1.0f);        \
    const float O_ = rcpa(1.0f + fexp2(ac##J[3]));                           \
    cs##J = fmaf(F_, cs##J, I_ * G_);                                        \
    const float tc_ = fmaf(2.0f, rcpa(1.0f + fexp2(cs##J * KS2f)), -1.0f);   \
    const float hv = O_ * tc_;                                               \
    hl##J = hv;                                                              \
    if (cell##J < Hn)                                                        \
      wsplit(&PH[wb][nl][(KO) + cell##J], &PL[wb][nl][(KO) + cell##J], hv);  \
  }

// aux cell update (cells 48/49, quad<2 valid)
#define AUX_CUP(PH, PL)                                                      \
  {                                                                          \
    const float I_ = rcpa(1.0f + fexp2(acA[0]));                             \
    const float F_ = rcpa(1.0f + fexp2(acA[1]));                             \
    const float G_ = fmaf(2.0f, rcpa(1.0f + fexp2(acA[2])), -1.0f);          \
    const float O_ = rcpa(1.0f + fexp2(acA[3]));                             \
    csA = fmaf(F_, csA, I_ * G_);                                            \
    const float tc_ = fmaf(2.0f, rcpa(1.0f + fexp2(csA * KS2f)), -1.0f);     \
    const float hv = O_ * tc_;                                               \
    hlA = hv;                                                                \
    if (cellA < Hn)                                                          \
      wsplit(&PH[wb][nl][cellA], &PL[wb][nl][cellA], hv);                    \
  }

__global__ __launch_bounds__(768, 3) void lstm_fused(
    const float* __restrict__ xg,    // [B][T]
    const float* __restrict__ wih1, const float* __restrict__ whh1,
    const float* __restrict__ b1, const float* __restrict__ wih2,
    const float* __restrict__ whh2, const float* __restrict__ b2,
    const float* __restrict__ wih3, const float* __restrict__ whh3,
    const float* __restrict__ b3, const float* __restrict__ wfc,
    const float* __restrict__ bfc, float* __restrict__ out)  // [B]
{
  __shared__ __align__(16) short p1h[2][16][SW];  // [x | h1(1..50) | 1@51]
  __shared__ __align__(16) short p1l[2][16][SW];
  __shared__ __align__(16) short p2h[2][16][SW];  // [h2(0..49) | 1@50]
  __shared__ __align__(16) short p2l[2][16][SW];
  __shared__ __align__(16) short p3h[2][16][SW];  // [h3(0..49)]
  __shared__ __align__(16) short p3l[2][16][SW];
  __shared__ __align__(16) short8 s_f4j3[2][4][2][64];  // tile-12 frags [L-1][chunk][H/L][lane]
  __shared__ float s_fc[5][16];

  const int tid = threadIdx.x;
  const int w = tid >> 6;
  const int lane = tid & 63;
  const int quad = lane >> 4;
  const int nl = lane & 15;
  const int L = (w < 4) ? 0 : (w < 8) ? 1 : 2;
  const int wl = w & 3;
  const int wz2 = (L == 2) ? 1 : 0;
  const int eb = blockIdx.x * 16;
  const int cellA = 48 + quad;  // aux tile-12 cell

  const float* wihL = (L == 0) ? wih1 : (L == 1) ? wih2 : wih3;
  const float* whhL = (L == 0) ? whh1 : (L == 1) ? whh2 : whh3;
  const float* biasL = (L == 0) ? b1 : (L == 1) ? b2 : b3;

  LW(0) LW(1) LW(2) LW(3) LW(4) LW(5) LW(6) LW(7)
  LW(8) LW(9) LW(10) LW(11)
  LW(16) LW(17) LW(18) LW(19)

  // J2 fragments -> AGPR-resident values (used only via "a"-constrained asm)
  short8 aj2h0 = FH8,  aj2l0 = FL8;
  short8 aj2h1 = FH9,  aj2l1 = FL9;
  short8 aj2h2 = FH10, aj2l2 = FL10;
  short8 aj2h3 = FH11, aj2l3 = FL11;

  // park tile-12 fragments in LDS for the aux waves; registers die here
  if (L > 0 && wl == 0) {
    s_f4j3[wz2][0][0][lane] = FH16; s_f4j3[wz2][0][1][lane] = FL16;
    s_f4j3[wz2][1][0][lane] = FH17; s_f4j3[wz2][1][1][lane] = FL17;
    s_f4j3[wz2][2][0][lane] = FH18; s_f4j3[wz2][2][1][lane] = FL18;
    s_f4j3[wz2][3][0][lane] = FH19; s_f4j3[wz2][3][1][lane] = FL19;
  }

  BINIT(0) BINIT(1) BINIT(2) BINIT(3)
  float csA = 0.f, hlA = 0.f;  // aux tile-12 state (L1-w1: L2; L1-w2: L3)

  for (int i = tid; i < 2 * 16 * SW; i += 768) {
    (&p1h[0][0][0])[i] = 0;
    (&p1l[0][0][0])[i] = 0;
    (&p2h[0][0][0])[i] = 0;
    (&p2l[0][0][0])[i] = 0;
    (&p3h[0][0][0])[i] = 0;
    (&p3l[0][0][0])[i] = 0;
  }
  __syncthreads();
  if (w == 0 && lane < 16) {
    const float xv = xg[(size_t)(eb + lane) * Tn + 0];
    wsplit(&p1h[0][lane][0], &p1l[0][lane][0], xv);
  }
  // constant-1 bias slots (both buffers; never overwritten: p1 h/x writes
  // touch k=0..50 only, p2 h writes touch k=0..49 only)
  if (tid < 32) {
    const int bb = tid >> 4, bn = tid & 15;
    p1h[bb][bn][51] = (short)0x3F80;  // 1.0f high half (low plane stays 0)
    p2h[bb][bn][50] = (short)0x3F80;
  }
  __syncthreads();

#pragma unroll 1
  for (int i = 0; i < Tn + 2; ++i) {
    const int rb = i & 1, wb = rb ^ 1;
    if (L == 0) {
      if (i < Tn) {
        float xv = 0.f;
        if (w == 0 && lane < 16 && i + 1 < Tn)
          xv = xg[(size_t)(eb + lane) * Tn + (i + 1)];
        f32x4 ac0 = {0.f, 0.f, 0.f, 0.f};
        f32x4 ac1 = {0.f, 0.f, 0.f, 0.f};
        f32x4 ac2 = {0.f, 0.f, 0.f, 0.f};
        f32x4 ac3 = {0.f, 0.f, 0.f, 0.f};
        __builtin_amdgcn_s_setprio(1);
        MCH_L1(0, 0, 2, 4, 6)
        MCH_L1(1, 1, 3, 5, 7)   // chunk 1 carries bias@51
        __builtin_amdgcn_s_setprio(0);
        CUP(0, p1h, p1l, 1)
        CUP(1, p1h, p1l, 1)
        CUP(2, p1h, p1l, 1)
        CUP(3, p1h, p1l, 1)
        if (w == 0 && lane < 16)
          wsplit(&p1h[wb][lane][0], &p1l[wb][lane][0], xv);
      }
      if (wl == 1 && i >= 1 && i <= Tn) {  // aux: L2 tile 12
        f32x4 acA = {0.f, 0.f, 0.f, 0.f};
        __builtin_amdgcn_s_setprio(1);
        AUX_MCH(0, p1h, p1l, 0, 0)
        AUX_MCH(0, p1h, p1l, 1, 1)   // bias@51
        AUX_MCH(0, p2h, p2l, 0, 2)
        AUX_MCH(0, p2h, p2l, 1, 3)
        __builtin_amdgcn_s_setprio(0);
        AUX_CUP(p2h, p2l)
      }
      if (wl == 2 && i >= 2) {  // aux: L3 tile 12
        f32x4 acA = {0.f, 0.f, 0.f, 0.f};
        __builtin_amdgcn_s_setprio(1);
        AUX_MCH(1, p2h, p2l, 0, 0)
        AUX_MCH(1, p2h, p2l, 1, 1)   // bias@50
        AUX_MCH(1, p3h, p3l, 0, 2)
        AUX_MCH(1, p3h, p3l, 1, 3)
        __builtin_amdgcn_s_setprio(0);
        AUX_CUP(p3h, p3l)
      }
    } else if (L == 1) {
      if (i >= 1 && i <= Tn) {
        f32x4 ac0 = {0.f, 0.f, 0.f, 0.f};
        f32x4 ac1 = {0.f, 0.f, 0.f, 0.f};
        f32x4 ac2 = {0.f, 0.f, 0.f, 0.f};
        __builtin_amdgcn_s_setprio(1);
        MCH_L23(p1h, p1l, 0, 0, 0, 4)    // combined k 0..31  (h1)
        MCH_L23(p1h, p1l, 1, 1, 1, 5)    // combined k 32..63 (h1 + bias@51)
        MCH_L23(p2h, p2l, 0, 2, 2, 6)    // combined k 64..95 (h2)
        MCH_L23E(p2h, p2l, 1, 3, 3, 7)   // combined k 96..127(h2) + fence
        __builtin_amdgcn_s_setprio(0);
        CUP(0, p2h, p2l, 0)
        CUP(1, p2h, p2l, 0)
        CUP(2, p2h, p2l, 0)
      }
    } else {
      if (i >= 2) {
        f32x4 ac0 = {0.f, 0.f, 0.f, 0.f};
        f32x4 ac1 = {0.f, 0.f, 0.f, 0.f};
        f32x4 ac2 = {0.f, 0.f, 0.f, 0.f};
        __builtin_amdgcn_s_setprio(1);
        MCH_L23(p2h, p2l, 0, 0, 0, 4)    // h2 k 0..31
        MCH_L23(p2h, p2l, 1, 1, 1, 5)    // h2 k 32..63 (+ bias@50)
        MCH_L23(p3h, p3l, 0, 2, 2, 6)    // h3
        MCH_L23E(p3h, p3l, 1, 3, 3, 7)   // h3 + fence
        __builtin_amdgcn_s_setprio(0);
        CUP(0, p3h, p3l, 0)
        CUP(1, p3h, p3l, 0)
        CUP(2, p3h, p3l, 0)
      }
    }
    __syncthreads();
  }

  if (L == 2) {
    float pfc = 0.f;
    if (tv0 && cell0 < Hn) pfc += hl0 * wfc[cell0];
    if (tv1 && cell1 < Hn) pfc += hl1 * wfc[cell1];
    if (tv2 && cell2 < Hn) pfc += hl2 * wfc[cell2];
    pfc += __shfl_xor(pfc, 16);  // sum over quads (cells)
    pfc += __shfl_xor(pfc, 32);
    if (lane < 16) s_fc[wl][lane] = pfc;
  }
  if (L == 0 && wl == 2) {  // aux L3 tile-12 (cells 48,49)
    float pfcA = 0.f;
    if (quad < 2) pfcA = hlA * wfc[cellA];
    pfcA += __shfl_xor(pfcA, 16);
    pfcA += __shfl_xor(pfcA, 32);
    if (lane < 16) s_fc[4][lane] = pfcA;
  }
  __syncthreads();
  if (tid < 16)
    out[eb + tid] = bfc[0] + s_fc[0][tid] + s_fc[1][tid] + s_fc[2][tid] +
                    s_fc[3][tid] + s_fc[4][tid];
}

}  // namespace

extern "C" void kernel_launch(void* const* d_in, const int* in_sizes, int n_in,
                              void* d_out, int out_size, void* d_ws, size_t ws_size,
                              hipStream_t stream) {
  const float* x    = (const float*)d_in[0];
  const float* wih1 = (const float*)d_in[1];
  const float* whh1 = (const float*)d_in[2];
  const float* b1   = (const float*)d_in[3];
  const float* wih2 = (const float*)d_in[4];
  const float* whh2 = (const float*)d_in[5];
  const float* b2   = (const float*)d_in[6];
  const float* wih3 = (const float*)d_in[7];
  const float* whh3 = (const float*)d_in[8];
  const float* b3   = (const float*)d_in[9];
  const float* wfc  = (const float*)d_in[10];
  const float* bfc  = (const float*)d_in[11];
  float* out = (float*)d_out;

  lstm_fused<<<dim3(Bn / 16), dim3(768), 0, stream>>>(
      x, wih1, whh1, b1, wih2, whh2, b2, wih3, whh3, b3, wfc, bfc, out);
}

// Round 20
// 772.922 us; speedup vs baseline: 1.1306x; 1.1306x over previous
//
#include <hip/hip_runtime.h>
#include <math.h>

namespace {

constexpr int Hn = 50;    // hidden size
constexpr int Bn = 2048;  // batch
constexpr int Tn = 512;   // sequence length
constexpr int SW = 72;    // plane row stride in shorts (144 B)

constexpr float KS1f = -1.44269504088896340736f;  // -log2(e)   (sigmoid rows i,f,o)
constexpr float KS2f = -2.88539008177792681472f;  // -2*log2(e) (tanh row g, and tanh(c))

typedef short short8 __attribute__((ext_vector_type(8)));
typedef float f32x4 __attribute__((ext_vector_type(4)));

__device__ __forceinline__ unsigned bcu(float f) { return __builtin_bit_cast(unsigned, f); }
__device__ __forceinline__ float bcf(unsigned u) { return __builtin_bit_cast(float, u); }
__device__ __forceinline__ float rcpa(float x) { return __builtin_amdgcn_rcpf(x); }

__device__ __forceinline__ float fexp2(float x) {
#if defined(__has_builtin)
#if __has_builtin(__builtin_amdgcn_exp2f)
  return __builtin_amdgcn_exp2f(x);
#else
  return exp2f(x);
#endif
#else
  return exp2f(x);
#endif
}

__device__ __forceinline__ void wsplit(short* ph, short* pl, float v) {
  const unsigned u = bcu(v);
  *ph = (short)(u >> 16);
  *pl = (short)(bcu(v - bcf(u & 0xFFFF0000u)) >> 16);
}

#define MF(a, b, c) __builtin_amdgcn_mfma_f32_16x16x32_bf16(a, b, c, 0, 0, 0)

// ============================================================================
// FUSED 3-layer LSTM + FC, systolic in time. R27 = R23 RESTORED (767us, the
// session's verified best; 2.2x faster than the 1546us session start).
// Search-tree closure (all measured):
//  - Weights beyond 8 reg-pairs -> spills. Allocator model: with MFMA accs
//    live the unified file splits cap/2 arch + cap/2 AGPR (R10/12/14/16/19).
//  - Weights in AGPRs: unreachable. Builtin MFMA inserts v_accvgpr_read
//    copies (R21); inline-asm MFMA races without fences (R25, absmax 2.9e-3)
//    and spills with them (R26: WRITE 6920KB, -107us vs R23). Door closed.
//  - LDS-parked weights: LDS pipe binding (R15 audit ~2200cy/iter; R24's
//    +64 reads regressed -43us, conflicts 3.5->5.2e7). Marginal LDS-cut
//    rate ~20% (R22: -48 reads -> -22us) caps remaining upside at ~3%.
//  - Issue order: term-major refuted (R13), stagger refuted (R24),
//    setprio neutral-kept (R20). Cross-block pipeline: hangs (R17/R18).
// Structure: 128 blk x 768 thr (12 waves, 3/SIMD, zero spills).
//  - L1: 4 waves, tiles wl+4J (2 chunks, reg); w1/w2 carry AUX roles:
//    w1 = L2 tile 12, w2 = L3 tile 12, frags from s_f4j3 (critical-wave
//    rebalance: max MFMA/wave 48 -> 36, -16%).
//  - L2/L3: 4 waves each; tiles wl, wl+4 reg (4 chunks); J2 tile wl+8 from
//    LDS s_f4j2.
//  - bias via MFMA k-slot: planes carry 1.0 at p1[51] / p2[50]; prescaled
//    bias sits in the weight frags at that k; acc init = 0 (-48 LDS
//    reads/iter, absmax 2.4414e-4).
//  - exp2-prescaled weights (sigmoid rows * -log2e, tanh rows * -2log2e):
//    gates = rcp(1+exp2(z')), tanh = 2*rcp(1+e)-1.
//  - fp32 accuracy via 3-term split-bf16 (Wh*Uh + Wl*Uh + Wh*Ul); planes
//    K=64: P1=[x,h1(1..50),1@51], P2=[h2,1@50], P3=[h3]; ONE barrier/iter.
// ============================================================================

#define LW(FI)                                                               \
  short8 FH##FI = {0, 0, 0, 0, 0, 0, 0, 0};                                  \
  short8 FL##FI = {0, 0, 0, 0, 0, 0, 0, 0};                                  \
  {                                                                          \
    const int tile_ =                                                        \
        ((FI) >= 16) ? ((L == 0 || wl != 0) ? 13 : 12)                       \
        : ((FI) >= 8) ? ((L == 0) ? 13 : (wl + 8))                           \
        : (L == 0)    ? (wl + 4 * ((FI) >> 1))                               \
                      : (wl + 4 * ((FI) >> 2));                              \
    const int chunk_ = ((FI) >= 8) ? ((FI)&3)                                \
                       : (L == 0)  ? ((FI)&1)                                \
                                   : ((FI)&3);                               \
    const int cb_ = 4 * tile_ + (nl >> 2);                                   \
    if (tile_ < 13 && cb_ < Hn) {                                            \
      const int row_ = (nl & 3) * Hn + cb_;                                  \
      const float sc_ = ((nl & 3) == 2) ? KS2f : KS1f;                       \
      _Pragma("unroll") for (int jj = 0; jj < 8; ++jj) {                     \
        const int k_ = 32 * chunk_ + quad * 8 + jj;                          \
        float wv = 0.f;                                                      \
        if (L == 0) {                                                        \
          if (k_ == 0) wv = wihL[row_];                                      \
          else if (k_ <= Hn) wv = whhL[row_ * Hn + k_ - 1];                  \
          else if (k_ == 51) wv = biasL[row_];                               \
        } else if (L == 1) {                                                 \
          if (k_ >= 1 && k_ <= Hn) wv = wihL[row_ * Hn + k_ - 1];            \
          else if (k_ == 51) wv = biasL[row_];                               \
          else if (k_ >= 64 && k_ < 64 + Hn) wv = whhL[row_ * Hn + k_ - 64]; \
        } else {                                                             \
          if (k_ < Hn) wv = wihL[row_ * Hn + k_];                            \
          else if (k_ == Hn) wv = biasL[row_];                               \
          else if (k_ >= 64 && k_ < 64 + Hn) wv = whhL[row_ * Hn + k_ - 64]; \
        }                                                                    \
        wv *= sc_;                                                           \
        const unsigned uu = bcu(wv);                                         \
        FH##FI[jj] = (short)(uu >> 16);                                      \
        FL##FI[jj] = (short)(bcu(wv - bcf(uu & 0xFFFF0000u)) >> 16);         \
      }                                                                      \
    }                                                                        \
  }

#define BINIT(J)                                                             \
  const int tile##J = wl + 4 * (J);                                          \
  const int tv##J = tile##J < 13;                                            \
  const int cell##J = 4 * tile##J + quad;                                    \
  float cs##J = 0.f, hl##J = 0.f;

// tile-major triplet (R13-proven: dependent same-acc MFMAs are free)
#define MTM(J, FI)                                                           \
  if (tv##J) {                                                               \
    ac##J = MF(FH##FI, uh_, ac##J);                                          \
    ac##J = MF(FL##FI, uh_, ac##J);                                          \
    ac##J = MF(FH##FI, ul_, ac##J);                                          \
  }

// J2 (tiles 8..11, all L2/3 waves) from LDS
#define MTMS2(CI)                                                            \
  {                                                                          \
    const short8 fh_ = s_f4j2[wz2][wl][CI][0][lane];                         \
    const short8 fl_ = s_f4j2[wz2][wl][CI][1][lane];                         \
    ac2 = MF(fh_, uh_, ac2);                                                 \
    ac2 = MF(fl_, uh_, ac2);                                                 \
    ac2 = MF(fh_, ul_, ac2);                                                 \
  }

#define MCH_L1(LC, F0, F1, F2, F3)                                           \
  {                                                                          \
    const short8 uh_ = *(const short8*)&p1h[rb][nl][32 * (LC) + quad * 8];   \
    const short8 ul_ = *(const short8*)&p1l[rb][nl][32 * (LC) + quad * 8];   \
    MTM(0, F0) MTM(1, F1) MTM(2, F2) MTM(3, F3)                              \
  }

// L2/L3 chunk: J0,J1 reg + J2 LDS (tile 12 lives on aux L1 waves)
#define MCH_L23(PH, PL, LC, CI, F0, F1)                                      \
  {                                                                          \
    const short8 uh_ = *(const short8*)&PH[rb][nl][32 * (LC) + quad * 8];    \
    const short8 ul_ = *(const short8*)&PL[rb][nl][32 * (LC) + quad * 8];    \
    MTM(0, F0) MTM(1, F1) MTMS2(CI)                                          \
  }

// aux chunk (L1-w1 = L2 tile 12 via s_f4j3[0]; L1-w2 = L3 tile 12 via [1])
#define AUX_MCH(AZ, PH, PL, LC, CI)                                          \
  {                                                                          \
    const short8 uh_ = *(const short8*)&PH[rb][nl][32 * (LC) + quad * 8];    \
    const short8 ul_ = *(const short8*)&PL[rb][nl][32 * (LC) + quad * 8];    \
    const short8 fh_ = s_f4j3[AZ][CI][0][lane];                              \
    const short8 fl_ = s_f4j3[AZ][CI][1][lane];                              \
    acA = MF(fh_, uh_, acA);                                                 \
    acA = MF(fl_, uh_, acA);                                                 \
    acA = MF(fh_, ul_, acA);                                                 \
  }

// cell update for tile J; SINGLE h write into plane (PH,PL) at k = KO+cell
#define CUP(J, PH, PL, KO)                                                   \
  if (tv##J) {                                                               \
    const float I_ = rcpa(1.0f + fexp2(ac##J[0]));                           \
    const float F_ = rcpa(1.0f + fexp2(ac##J[1]));                           \
    const float G_ = fmaf(2.0f, rcpa(1.0f + fexp2(ac##J[2])), -1.0f);        \
    const float O_ = rcpa(1.0f + fexp2(ac##J[3]));                           \
    cs##J = fmaf(F_, cs##J, I_ * G_);                                        \
    const float tc_ = fmaf(2.0f, rcpa(1.0f + fexp2(cs##J * KS2f)), -1.0f);   \
    const float hv = O_ * tc_;                                               \
    hl##J = hv;                                                              \
    if (cell##J < Hn)                                                        \
      wsplit(&PH[wb][nl][(KO) + cell##J], &PL[wb][nl][(KO) + cell##J], hv);  \
  }

// aux cell update (cells 48/49, quad<2 valid)
#define AUX_CUP(PH, PL)                                                      \
  {                                                                          \
    const float I_ = rcpa(1.0f + fexp2(acA[0]));                             \
    const float F_ = rcpa(1.0f + fexp2(acA[1]));                             \
    const float G_ = fmaf(2.0f, rcpa(1.0f + fexp2(acA[2])), -1.0f);          \
    const float O_ = rcpa(1.0f + fexp2(acA[3]));                             \
    csA = fmaf(F_, csA, I_ * G_);                                            \
    const float tc_ = fmaf(2.0f, rcpa(1.0f + fexp2(csA * KS2f)), -1.0f);     \
    const float hv = O_ * tc_;                                               \
    hlA = hv;                                                                \
    if (cellA < Hn)                                                          \
      wsplit(&PH[wb][nl][cellA], &PL[wb][nl][cellA], hv);                    \
  }

__global__ __launch_bounds__(768, 3) void lstm_fused(
    const float* __restrict__ xg,    // [B][T]
    const float* __restrict__ wih1, const float* __restrict__ whh1,
    const float* __restrict__ b1, const float* __restrict__ wih2,
    const float* __restrict__ whh2, const float* __restrict__ b2,
    const float* __restrict__ wih3, const float* __restrict__ whh3,
    const float* __restrict__ b3, const float* __restrict__ wfc,
    const float* __restrict__ bfc, float* __restrict__ out)  // [B]
{
  __shared__ __align__(16) short p1h[2][16][SW];  // [x | h1(1..50) | 1@51]
  __shared__ __align__(16) short p1l[2][16][SW];
  __shared__ __align__(16) short p2h[2][16][SW];  // [h2(0..49) | 1@50]
  __shared__ __align__(16) short p2l[2][16][SW];
  __shared__ __align__(16) short p3h[2][16][SW];  // [h3(0..49)]
  __shared__ __align__(16) short p3l[2][16][SW];
  __shared__ __align__(16) short8 s_f4j2[2][4][4][2][64];  // J2 frags [L-1][wl][chunk][H/L][lane]
  __shared__ __align__(16) short8 s_f4j3[2][4][2][64];     // tile-12 frags [L-1][chunk][H/L][lane]
  __shared__ float s_fc[5][16];

  const int tid = threadIdx.x;
  const int w = tid >> 6;
  const int lane = tid & 63;
  const int quad = lane >> 4;
  const int nl = lane & 15;
  const int L = (w < 4) ? 0 : (w < 8) ? 1 : 2;
  const int wl = w & 3;
  const int wz2 = (L == 2) ? 1 : 0;
  const int eb = blockIdx.x * 16;
  const int cellA = 48 + quad;  // aux tile-12 cell

  const float* wihL = (L == 0) ? wih1 : (L == 1) ? wih2 : wih3;
  const float* whhL = (L == 0) ? whh1 : (L == 1) ? whh2 : whh3;
  const float* biasL = (L == 0) ? b1 : (L == 1) ? b2 : b3;

  LW(0) LW(1) LW(2) LW(3) LW(4) LW(5) LW(6) LW(7)
  LW(8) LW(9) LW(10) LW(11)
  LW(16) LW(17) LW(18) LW(19)

  // park J2 + tile-12 fragments in LDS; their registers die here
  if (L > 0) {
    s_f4j2[wz2][wl][0][0][lane] = FH8;  s_f4j2[wz2][wl][0][1][lane] = FL8;
    s_f4j2[wz2][wl][1][0][lane] = FH9;  s_f4j2[wz2][wl][1][1][lane] = FL9;
    s_f4j2[wz2][wl][2][0][lane] = FH10; s_f4j2[wz2][wl][2][1][lane] = FL10;
    s_f4j2[wz2][wl][3][0][lane] = FH11; s_f4j2[wz2][wl][3][1][lane] = FL11;
    if (wl == 0) {
      s_f4j3[wz2][0][0][lane] = FH16; s_f4j3[wz2][0][1][lane] = FL16;
      s_f4j3[wz2][1][0][lane] = FH17; s_f4j3[wz2][1][1][lane] = FL17;
      s_f4j3[wz2][2][0][lane] = FH18; s_f4j3[wz2][2][1][lane] = FL18;
      s_f4j3[wz2][3][0][lane] = FH19; s_f4j3[wz2][3][1][lane] = FL19;
    }
  }

  BINIT(0) BINIT(1) BINIT(2) BINIT(3)
  float csA = 0.f, hlA = 0.f;  // aux tile-12 state (L1-w1: L2; L1-w2: L3)

  for (int i = tid; i < 2 * 16 * SW; i += 768) {
    (&p1h[0][0][0])[i] = 0;
    (&p1l[0][0][0])[i] = 0;
    (&p2h[0][0][0])[i] = 0;
    (&p2l[0][0][0])[i] = 0;
    (&p3h[0][0][0])[i] = 0;
    (&p3l[0][0][0])[i] = 0;
  }
  __syncthreads();
  if (w == 0 && lane < 16) {
    const float xv = xg[(size_t)(eb + lane) * Tn + 0];
    wsplit(&p1h[0][lane][0], &p1l[0][lane][0], xv);
  }
  // constant-1 bias slots (both buffers; never overwritten: p1 h/x writes
  // touch k=0..50 only, p2 h writes touch k=0..49 only)
  if (tid < 32) {
    const int bb = tid >> 4, bn = tid & 15;
    p1h[bb][bn][51] = (short)0x3F80;  // 1.0f high half (low plane stays 0)
    p2h[bb][bn][50] = (short)0x3F80;
  }
  __syncthreads();

#pragma unroll 1
  for (int i = 0; i < Tn + 2; ++i) {
    const int rb = i & 1, wb = rb ^ 1;
    if (L == 0) {
      if (i < Tn) {
        float xv = 0.f;
        if (w == 0 && lane < 16 && i + 1 < Tn)
          xv = xg[(size_t)(eb + lane) * Tn + (i + 1)];
        f32x4 ac0 = {0.f, 0.f, 0.f, 0.f};
        f32x4 ac1 = {0.f, 0.f, 0.f, 0.f};
        f32x4 ac2 = {0.f, 0.f, 0.f, 0.f};
        f32x4 ac3 = {0.f, 0.f, 0.f, 0.f};
        __builtin_amdgcn_s_setprio(1);
        MCH_L1(0, 0, 2, 4, 6)
        MCH_L1(1, 1, 3, 5, 7)   // chunk 1 carries bias@51
        __builtin_amdgcn_s_setprio(0);
        CUP(0, p1h, p1l, 1)
        CUP(1, p1h, p1l, 1)
        CUP(2, p1h, p1l, 1)
        CUP(3, p1h, p1l, 1)
        if (w == 0 && lane < 16)
          wsplit(&p1h[wb][lane][0], &p1l[wb][lane][0], xv);
      }
      if (wl == 1 && i >= 1 && i <= Tn) {  // aux: L2 tile 12
        f32x4 acA = {0.f, 0.f, 0.f, 0.f};
        __builtin_amdgcn_s_setprio(1);
        AUX_MCH(0, p1h, p1l, 0, 0)
        AUX_MCH(0, p1h, p1l, 1, 1)   // bias@51
        AUX_MCH(0, p2h, p2l, 0, 2)
        AUX_MCH(0, p2h, p2l, 1, 3)
        __builtin_amdgcn_s_setprio(0);
        AUX_CUP(p2h, p2l)
      }
      if (wl == 2 && i >= 2) {  // aux: L3 tile 12
        f32x4 acA = {0.f, 0.f, 0.f, 0.f};
        __builtin_amdgcn_s_setprio(1);
        AUX_MCH(1, p2h, p2l, 0, 0)
        AUX_MCH(1, p2h, p2l, 1, 1)   // bias@50
        AUX_MCH(1, p3h, p3l, 0, 2)
        AUX_MCH(1, p3h, p3l, 1, 3)
        __builtin_amdgcn_s_setprio(0);
        AUX_CUP(p3h, p3l)
      }
    } else if (L == 1) {
      if (i >= 1 && i <= Tn) {
        f32x4 ac0 = {0.f, 0.f, 0.f, 0.f};
        f32x4 ac1 = {0.f, 0.f, 0.f, 0.f};
        f32x4 ac2 = {0.f, 0.f, 0.f, 0.f};
        __builtin_amdgcn_s_setprio(1);
        MCH_L23(p1h, p1l, 0, 0, 0, 4)   // combined k 0..31  (h1)
        MCH_L23(p1h, p1l, 1, 1, 1, 5)   // combined k 32..63 (h1 + bias@51)
        MCH_L23(p2h, p2l, 0, 2, 2, 6)   // combined k 64..95 (h2)
        MCH_L23(p2h, p2l, 1, 3, 3, 7)   // combined k 96..127(h2)
        __builtin_amdgcn_s_setprio(0);
        CUP(0, p2h, p2l, 0)
        CUP(1, p2h, p2l, 0)
        CUP(2, p2h, p2l, 0)
      }
    } else {
      if (i >= 2) {
        f32x4 ac0 = {0.f, 0.f, 0.f, 0.f};
        f32x4 ac1 = {0.f, 0.f, 0.f, 0.f};
        f32x4 ac2 = {0.f, 0.f, 0.f, 0.f};
        __builtin_amdgcn_s_setprio(1);
        MCH_L23(p2h, p2l, 0, 0, 0, 4)   // h2 k 0..31
        MCH_L23(p2h, p2l, 1, 1, 1, 5)   // h2 k 32..63 (+ bias@50)
        MCH_L23(p3h, p3l, 0, 2, 2, 6)   // h3
        MCH_L23(p3h, p3l, 1, 3, 3, 7)
        __builtin_amdgcn_s_setprio(0);
        CUP(0, p3h, p3l, 0)
        CUP(1, p3h, p3l, 0)
        CUP(2, p3h, p3l, 0)
      }
    }
    __syncthreads();
  }

  if (L == 2) {
    float pfc = 0.f;
    if (tv0 && cell0 < Hn) pfc += hl0 * wfc[cell0];
    if (tv1 && cell1 < Hn) pfc += hl1 * wfc[cell1];
    if (tv2 && cell2 < Hn) pfc += hl2 * wfc[cell2];
    pfc += __shfl_xor(pfc, 16);  // sum over quads (cells)
    pfc += __shfl_xor(pfc, 32);
    if (lane < 16) s_fc[wl][lane] = pfc;
  }
  if (L == 0 && wl == 2) {  // aux L3 tile-12 (cells 48,49)
    float pfcA = 0.f;
    if (quad < 2) pfcA = hlA * wfc[cellA];
    pfcA += __shfl_xor(pfcA, 16);
    pfcA += __shfl_xor(pfcA, 32);
    if (lane < 16) s_fc[4][lane] = pfcA;
  }
  __syncthreads();
  if (tid < 16)
    out[eb + tid] = bfc[0] + s_fc[0][tid] + s_fc[1][tid] + s_fc[2][tid] +
                    s_fc[3][tid] + s_fc[4][tid];
}

}  // namespace

extern "C" void kernel_launch(void* const* d_in, const int* in_sizes, int n_in,
                              void* d_out, int out_size, void* d_ws, size_t ws_size,
                              hipStream_t stream) {
  const float* x    = (const float*)d_in[0];
  const float* wih1 = (const float*)d_in[1];
  const float* whh1 = (const float*)d_in[2];
  const float* b1   = (const float*)d_in[3];
  const float* wih2 = (const float*)d_in[4];
  const float* whh2 = (const float*)d_in[5];
  const float* b2   = (const float*)d_in[6];
  const float* wih3 = (const float*)d_in[7];
  const float* whh3 = (const float*)d_in[8];
  const float* b3   = (const float*)d_in[9];
  const float* wfc  = (const float*)d_in[10];
  const float* bfc  = (const float*)d_in[11];
  float* out = (float*)d_out;

  lstm_fused<<<dim3(Bn / 16), dim3(768), 0, stream>>>(
      x, wih1, whh1, b1, wih2, whh2, b2, wih3, whh3, b3, wfc, bfc, out);
}

// Round 21
// 766.180 us; speedup vs baseline: 1.1406x; 1.0088x over previous
//
#include <hip/hip_runtime.h>
#include <math.h>

namespace {

constexpr int Hn = 50;    // hidden size
constexpr int Bn = 2048;  // batch
constexpr int Tn = 512;   // sequence length
constexpr int SW = 72;    // plane row stride in shorts (144 B)

constexpr float KS1f = -1.44269504088896340736f;  // -log2(e)   (sigmoid rows i,f,o)
constexpr float KS2f = -2.88539008177792681472f;  // -2*log2(e) (tanh row g, and tanh(c))

typedef short short8 __attribute__((ext_vector_type(8)));
typedef float f32x4 __attribute__((ext_vector_type(4)));

__device__ __forceinline__ unsigned bcu(float f) { return __builtin_bit_cast(unsigned, f); }
__device__ __forceinline__ float bcf(unsigned u) { return __builtin_bit_cast(float, u); }
__device__ __forceinline__ float rcpa(float x) { return __builtin_amdgcn_rcpf(x); }

__device__ __forceinline__ float fexp2(float x) {
#if defined(__has_builtin)
#if __has_builtin(__builtin_amdgcn_exp2f)
  return __builtin_amdgcn_exp2f(x);
#else
  return exp2f(x);
#endif
#else
  return exp2f(x);
#endif
}

__device__ __forceinline__ void wsplit(short* ph, short* pl, float v) {
  const unsigned u = bcu(v);
  *ph = (short)(u >> 16);
  *pl = (short)(bcu(v - bcf(u & 0xFFFF0000u)) >> 16);
}

#define MF(a, b, c) __builtin_amdgcn_mfma_f32_16x16x32_bf16(a, b, c, 0, 0, 0)

// ============================================================================
// FUSED 3-layer LSTM + FC, systolic in time. FINAL (R23 structure; verified
// 767-773us across two independent runs; 2.0x the session-start 1546us).
// Search-tree closure (all measured this session):
//  - MFMA balance at integer optimum: 390 MFMA/iter over 12 waves, tile
//    quantum 12 -> max/wave 36 (achieved). No redistribution lowers it.
//  - K-chunks floor: L2/L3 real K = 100-101 slots > 96 (3 chunks) -> 4.
//  - Weights beyond 8 reg-pairs spill: allocator splits unified file cap/2
//    arch + cap/2 AGPR when MFMA accs live (R10/12/14/16/19).
//  - Weights in AGPRs unreachable: builtin copies via v_accvgpr_read (R21);
//    asm MFMA races unfenced (R25) and spills fenced (R26).
//  - More LDS parking hurts: LDS pipe binding (R15 audit; R24 +reads
//    regressed, conflicts 3.5->5.2e7). Marginal LDS-cut yield ~20% (R22).
//  - Issue order: term-major refuted (R13); stagger refuted (R24); setprio
//    neutral-kept (R20). Cross-block layer pipeline: hangs (R17/R18).
// Structure: 128 blk x 768 thr (12 waves, 3/SIMD, zero spills, VGPR 76).
//  - L1: 4 waves, tiles wl+4J (2 chunks, reg); w1/w2 carry AUX roles:
//    w1 = L2 tile 12, w2 = L3 tile 12, frags from s_f4j3 (critical-wave
//    rebalance: max MFMA/wave 48 -> 36, -16% = the session's biggest win).
//  - L2/L3: 4 waves each; tiles wl, wl+4 reg (4 chunks); J2 tile wl+8 from
//    LDS s_f4j2.
//  - bias via MFMA k-slot: planes carry 1.0 at p1[51] / p2[50]; prescaled
//    bias sits in the weight frags at that k; acc init = 0 (-48 LDS
//    reads/iter; absmax 2.4414e-4).
//  - exp2-prescaled weights (sigmoid rows * -log2e, tanh rows * -2log2e):
//    gates = rcp(1+exp2(z')), tanh = 2*rcp(1+e)-1.
//  - fp32 accuracy via 3-term split-bf16 (Wh*Uh + Wl*Uh + Wh*Ul); planes
//    K=64: P1=[x,h1(1..50),1@51], P2=[h2,1@50], P3=[h3]; ONE barrier/iter.
// ============================================================================

#define LW(FI)                                                               \
  short8 FH##FI = {0, 0, 0, 0, 0, 0, 0, 0};                                  \
  short8 FL##FI = {0, 0, 0, 0, 0, 0, 0, 0};                                  \
  {                                                                          \
    const int tile_ =                                                        \
        ((FI) >= 16) ? ((L == 0 || wl != 0) ? 13 : 12)                       \
        : ((FI) >= 8) ? ((L == 0) ? 13 : (wl + 8))                           \
        : (L == 0)    ? (wl + 4 * ((FI) >> 1))                               \
                      : (wl + 4 * ((FI) >> 2));                              \
    const int chunk_ = ((FI) >= 8) ? ((FI)&3)                                \
                       : (L == 0)  ? ((FI)&1)                                \
                                   : ((FI)&3);                               \
    const int cb_ = 4 * tile_ + (nl >> 2);                                   \
    if (tile_ < 13 && cb_ < Hn) {                                            \
      const int row_ = (nl & 3) * Hn + cb_;                                  \
      const float sc_ = ((nl & 3) == 2) ? KS2f : KS1f;                       \
      _Pragma("unroll") for (int jj = 0; jj < 8; ++jj) {                     \
        const int k_ = 32 * chunk_ + quad * 8 + jj;                          \
        float wv = 0.f;                                                      \
        if (L == 0) {                                                        \
          if (k_ == 0) wv = wihL[row_];                                      \
          else if (k_ <= Hn) wv = whhL[row_ * Hn + k_ - 1];                  \
          else if (k_ == 51) wv = biasL[row_];                               \
        } else if (L == 1) {                                                 \
          if (k_ >= 1 && k_ <= Hn) wv = wihL[row_ * Hn + k_ - 1];            \
          else if (k_ == 51) wv = biasL[row_];                               \
          else if (k_ >= 64 && k_ < 64 + Hn) wv = whhL[row_ * Hn + k_ - 64]; \
        } else {                                                             \
          if (k_ < Hn) wv = wihL[row_ * Hn + k_];                            \
          else if (k_ == Hn) wv = biasL[row_];                               \
          else if (k_ >= 64 && k_ < 64 + Hn) wv = whhL[row_ * Hn + k_ - 64]; \
        }                                                                    \
        wv *= sc_;                                                           \
        const unsigned uu = bcu(wv);                                         \
        FH##FI[jj] = (short)(uu >> 16);                                      \
        FL##FI[jj] = (short)(bcu(wv - bcf(uu & 0xFFFF0000u)) >> 16);         \
      }                                                                      \
    }                                                                        \
  }

#define BINIT(J)                                                             \
  const int tile##J = wl + 4 * (J);                                          \
  const int tv##J = tile##J < 13;                                            \
  const int cell##J = 4 * tile##J + quad;                                    \
  float cs##J = 0.f, hl##J = 0.f;

// tile-major triplet (R13-proven: dependent same-acc MFMAs are free)
#define MTM(J, FI)                                                           \
  if (tv##J) {                                                               \
    ac##J = MF(FH##FI, uh_, ac##J);                                          \
    ac##J = MF(FL##FI, uh_, ac##J);                                          \
    ac##J = MF(FH##FI, ul_, ac##J);                                          \
  }

// J2 (tiles 8..11, all L2/3 waves) from LDS
#define MTMS2(CI)                                                            \
  {                                                                          \
    const short8 fh_ = s_f4j2[wz2][wl][CI][0][lane];                         \
    const short8 fl_ = s_f4j2[wz2][wl][CI][1][lane];                         \
    ac2 = MF(fh_, uh_, ac2);                                                 \
    ac2 = MF(fl_, uh_, ac2);                                                 \
    ac2 = MF(fh_, ul_, ac2);                                                 \
  }

#define MCH_L1(LC, F0, F1, F2, F3)                                           \
  {                                                                          \
    const short8 uh_ = *(const short8*)&p1h[rb][nl][32 * (LC) + quad * 8];   \
    const short8 ul_ = *(const short8*)&p1l[rb][nl][32 * (LC) + quad * 8];   \
    MTM(0, F0) MTM(1, F1) MTM(2, F2) MTM(3, F3)                              \
  }

// L2/L3 chunk: J0,J1 reg + J2 LDS (tile 12 lives on aux L1 waves)
#define MCH_L23(PH, PL, LC, CI, F0, F1)                                      \
  {                                                                          \
    const short8 uh_ = *(const short8*)&PH[rb][nl][32 * (LC) + quad * 8];    \
    const short8 ul_ = *(const short8*)&PL[rb][nl][32 * (LC) + quad * 8];    \
    MTM(0, F0) MTM(1, F1) MTMS2(CI)                                          \
  }

// aux chunk (L1-w1 = L2 tile 12 via s_f4j3[0]; L1-w2 = L3 tile 12 via [1])
#define AUX_MCH(AZ, PH, PL, LC, CI)                                          \
  {                                                                          \
    const short8 uh_ = *(const short8*)&PH[rb][nl][32 * (LC) + quad * 8];    \
    const short8 ul_ = *(const short8*)&PL[rb][nl][32 * (LC) + quad * 8];    \
    const short8 fh_ = s_f4j3[AZ][CI][0][lane];                              \
    const short8 fl_ = s_f4j3[AZ][CI][1][lane];                              \
    acA = MF(fh_, uh_, acA);                                                 \
    acA = MF(fl_, uh_, acA);                                                 \
    acA = MF(fh_, ul_, acA);                                                 \
  }

// cell update for tile J; SINGLE h write into plane (PH,PL) at k = KO+cell
#define CUP(J, PH, PL, KO)                                                   \
  if (tv##J) {                                                               \
    const float I_ = rcpa(1.0f + fexp2(ac##J[0]));                           \
    const float F_ = rcpa(1.0f + fexp2(ac##J[1]));                           \
    const float G_ = fmaf(2.0f, rcpa(1.0f + fexp2(ac##J[2])), -1.0f);        \
    const float O_ = rcpa(1.0f + fexp2(ac##J[3]));                           \
    cs##J = fmaf(F_, cs##J, I_ * G_);                                        \
    const float tc_ = fmaf(2.0f, rcpa(1.0f + fexp2(cs##J * KS2f)), -1.0f);   \
    const float hv = O_ * tc_;                                               \
    hl##J = hv;                                                              \
    if (cell##J < Hn)                                                        \
      wsplit(&PH[wb][nl][(KO) + cell##J], &PL[wb][nl][(KO) + cell##J], hv);  \
  }

// aux cell update (cells 48/49, quad<2 valid)
#define AUX_CUP(PH, PL)                                                      \
  {                                                                          \
    const float I_ = rcpa(1.0f + fexp2(acA[0]));                             \
    const float F_ = rcpa(1.0f + fexp2(acA[1]));                             \
    const float G_ = fmaf(2.0f, rcpa(1.0f + fexp2(acA[2])), -1.0f);          \
    const float O_ = rcpa(1.0f + fexp2(acA[3]));                             \
    csA = fmaf(F_, csA, I_ * G_);                                            \
    const float tc_ = fmaf(2.0f, rcpa(1.0f + fexp2(csA * KS2f)), -1.0f);     \
    const float hv = O_ * tc_;                                               \
    hlA = hv;                                                                \
    if (cellA < Hn)                                                          \
      wsplit(&PH[wb][nl][cellA], &PL[wb][nl][cellA], hv);                    \
  }

__global__ __launch_bounds__(768, 3) void lstm_fused(
    const float* __restrict__ xg,    // [B][T]
    const float* __restrict__ wih1, const float* __restrict__ whh1,
    const float* __restrict__ b1, const float* __restrict__ wih2,
    const float* __restrict__ whh2, const float* __restrict__ b2,
    const float* __restrict__ wih3, const float* __restrict__ whh3,
    const float* __restrict__ b3, const float* __restrict__ wfc,
    const float* __restrict__ bfc, float* __restrict__ out)  // [B]
{
  __shared__ __align__(16) short p1h[2][16][SW];  // [x | h1(1..50) | 1@51]
  __shared__ __align__(16) short p1l[2][16][SW];
  __shared__ __align__(16) short p2h[2][16][SW];  // [h2(0..49) | 1@50]
  __shared__ __align__(16) short p2l[2][16][SW];
  __shared__ __align__(16) short p3h[2][16][SW];  // [h3(0..49)]
  __shared__ __align__(16) short p3l[2][16][SW];
  __shared__ __align__(16) short8 s_f4j2[2][4][4][2][64];  // J2 frags [L-1][wl][chunk][H/L][lane]
  __shared__ __align__(16) short8 s_f4j3[2][4][2][64];     // tile-12 frags [L-1][chunk][H/L][lane]
  __shared__ float s_fc[5][16];

  const int tid = threadIdx.x;
  const int w = tid >> 6;
  const int lane = tid & 63;
  const int quad = lane >> 4;
  const int nl = lane & 15;
  const int L = (w < 4) ? 0 : (w < 8) ? 1 : 2;
  const int wl = w & 3;
  const int wz2 = (L == 2) ? 1 : 0;
  const int eb = blockIdx.x * 16;
  const int cellA = 48 + quad;  // aux tile-12 cell

  const float* wihL = (L == 0) ? wih1 : (L == 1) ? wih2 : wih3;
  const float* whhL = (L == 0) ? whh1 : (L == 1) ? whh2 : whh3;
  const float* biasL = (L == 0) ? b1 : (L == 1) ? b2 : b3;

  LW(0) LW(1) LW(2) LW(3) LW(4) LW(5) LW(6) LW(7)
  LW(8) LW(9) LW(10) LW(11)
  LW(16) LW(17) LW(18) LW(19)

  // park J2 + tile-12 fragments in LDS; their registers die here
  if (L > 0) {
    s_f4j2[wz2][wl][0][0][lane] = FH8;  s_f4j2[wz2][wl][0][1][lane] = FL8;
    s_f4j2[wz2][wl][1][0][lane] = FH9;  s_f4j2[wz2][wl][1][1][lane] = FL9;
    s_f4j2[wz2][wl][2][0][lane] = FH10; s_f4j2[wz2][wl][2][1][lane] = FL10;
    s_f4j2[wz2][wl][3][0][lane] = FH11; s_f4j2[wz2][wl][3][1][lane] = FL11;
    if (wl == 0) {
      s_f4j3[wz2][0][0][lane] = FH16; s_f4j3[wz2][0][1][lane] = FL16;
      s_f4j3[wz2][1][0][lane] = FH17; s_f4j3[wz2][1][1][lane] = FL17;
      s_f4j3[wz2][2][0][lane] = FH18; s_f4j3[wz2][2][1][lane] = FL18;
      s_f4j3[wz2][3][0][lane] = FH19; s_f4j3[wz2][3][1][lane] = FL19;
    }
  }

  BINIT(0) BINIT(1) BINIT(2) BINIT(3)
  float csA = 0.f, hlA = 0.f;  // aux tile-12 state (L1-w1: L2; L1-w2: L3)

  for (int i = tid; i < 2 * 16 * SW; i += 768) {
    (&p1h[0][0][0])[i] = 0;
    (&p1l[0][0][0])[i] = 0;
    (&p2h[0][0][0])[i] = 0;
    (&p2l[0][0][0])[i] = 0;
    (&p3h[0][0][0])[i] = 0;
    (&p3l[0][0][0])[i] = 0;
  }
  __syncthreads();
  if (w == 0 && lane < 16) {
    const float xv = xg[(size_t)(eb + lane) * Tn + 0];
    wsplit(&p1h[0][lane][0], &p1l[0][lane][0], xv);
  }
  // constant-1 bias slots (both buffers; never overwritten: p1 h/x writes
  // touch k=0..50 only, p2 h writes touch k=0..49 only)
  if (tid < 32) {
    const int bb = tid >> 4, bn = tid & 15;
    p1h[bb][bn][51] = (short)0x3F80;  // 1.0f high half (low plane stays 0)
    p2h[bb][bn][50] = (short)0x3F80;
  }
  __syncthreads();

#pragma unroll 1
  for (int i = 0; i < Tn + 2; ++i) {
    const int rb = i & 1, wb = rb ^ 1;
    if (L == 0) {
      if (i < Tn) {
        float xv = 0.f;
        if (w == 0 && lane < 16 && i + 1 < Tn)
          xv = xg[(size_t)(eb + lane) * Tn + (i + 1)];
        f32x4 ac0 = {0.f, 0.f, 0.f, 0.f};
        f32x4 ac1 = {0.f, 0.f, 0.f, 0.f};
        f32x4 ac2 = {0.f, 0.f, 0.f, 0.f};
        f32x4 ac3 = {0.f, 0.f, 0.f, 0.f};
        __builtin_amdgcn_s_setprio(1);
        MCH_L1(0, 0, 2, 4, 6)
        MCH_L1(1, 1, 3, 5, 7)   // chunk 1 carries bias@51
        __builtin_amdgcn_s_setprio(0);
        CUP(0, p1h, p1l, 1)
        CUP(1, p1h, p1l, 1)
        CUP(2, p1h, p1l, 1)
        CUP(3, p1h, p1l, 1)
        if (w == 0 && lane < 16)
          wsplit(&p1h[wb][lane][0], &p1l[wb][lane][0], xv);
      }
      if (wl == 1 && i >= 1 && i <= Tn) {  // aux: L2 tile 12
        f32x4 acA = {0.f, 0.f, 0.f, 0.f};
        __builtin_amdgcn_s_setprio(1);
        AUX_MCH(0, p1h, p1l, 0, 0)
        AUX_MCH(0, p1h, p1l, 1, 1)   // bias@51
        AUX_MCH(0, p2h, p2l, 0, 2)
        AUX_MCH(0, p2h, p2l, 1, 3)
        __builtin_amdgcn_s_setprio(0);
        AUX_CUP(p2h, p2l)
      }
      if (wl == 2 && i >= 2) {  // aux: L3 tile 12
        f32x4 acA = {0.f, 0.f, 0.f, 0.f};
        __builtin_amdgcn_s_setprio(1);
        AUX_MCH(1, p2h, p2l, 0, 0)
        AUX_MCH(1, p2h, p2l, 1, 1)   // bias@50
        AUX_MCH(1, p3h, p3l, 0, 2)
        AUX_MCH(1, p3h, p3l, 1, 3)
        __builtin_amdgcn_s_setprio(0);
        AUX_CUP(p3h, p3l)
      }
    } else if (L == 1) {
      if (i >= 1 && i <= Tn) {
        f32x4 ac0 = {0.f, 0.f, 0.f, 0.f};
        f32x4 ac1 = {0.f, 0.f, 0.f, 0.f};
        f32x4 ac2 = {0.f, 0.f, 0.f, 0.f};
        __builtin_amdgcn_s_setprio(1);
        MCH_L23(p1h, p1l, 0, 0, 0, 4)   // combined k 0..31  (h1)
        MCH_L23(p1h, p1l, 1, 1, 1, 5)   // combined k 32..63 (h1 + bias@51)
        MCH_L23(p2h, p2l, 0, 2, 2, 6)   // combined k 64..95 (h2)
        MCH_L23(p2h, p2l, 1, 3, 3, 7)   // combined k 96..127(h2)
        __builtin_amdgcn_s_setprio(0);
        CUP(0, p2h, p2l, 0)
        CUP(1, p2h, p2l, 0)
        CUP(2, p2h, p2l, 0)
      }
    } else {
      if (i >= 2) {
        f32x4 ac0 = {0.f, 0.f, 0.f, 0.f};
        f32x4 ac1 = {0.f, 0.f, 0.f, 0.f};
        f32x4 ac2 = {0.f, 0.f, 0.f, 0.f};
        __builtin_amdgcn_s_setprio(1);
        MCH_L23(p2h, p2l, 0, 0, 0, 4)   // h2 k 0..31
        MCH_L23(p2h, p2l, 1, 1, 1, 5)   // h2 k 32..63 (+ bias@50)
        MCH_L23(p3h, p3l, 0, 2, 2, 6)   // h3
        MCH_L23(p3h, p3l, 1, 3, 3, 7)
        __builtin_amdgcn_s_setprio(0);
        CUP(0, p3h, p3l, 0)
        CUP(1, p3h, p3l, 0)
        CUP(2, p3h, p3l, 0)
      }
    }
    __syncthreads();
  }

  if (L == 2) {
    float pfc = 0.f;
    if (tv0 && cell0 < Hn) pfc += hl0 * wfc[cell0];
    if (tv1 && cell1 < Hn) pfc += hl1 * wfc[cell1];
    if (tv2 && cell2 < Hn) pfc += hl2 * wfc[cell2];
    pfc += __shfl_xor(pfc, 16);  // sum over quads (cells)
    pfc += __shfl_xor(pfc, 32);
    if (lane < 16) s_fc[wl][lane] = pfc;
  }
  if (L == 0 && wl == 2) {  // aux L3 tile-12 (cells 48,49)
    float pfcA = 0.f;
    if (quad < 2) pfcA = hlA * wfc[cellA];
    pfcA += __shfl_xor(pfcA, 16);
    pfcA += __shfl_xor(pfcA, 32);
    if (lane < 16) s_fc[4][lane] = pfcA;
  }
  __syncthreads();
  if (tid < 16)
    out[eb + tid] = bfc[0] + s_fc[0][tid] + s_fc[1][tid] + s_fc[2][tid] +
                    s_fc[3][tid] + s_fc[4][tid];
}

}  // namespace

extern "C" void kernel_launch(void* const* d_in, const int* in_sizes, int n_in,
                              void* d_out, int out_size, void* d_ws, size_t ws_size,
                              hipStream_t stream) {
  const float* x    = (const float*)d_in[0];
  const float* wih1 = (const float*)d_in[1];
  const float* whh1 = (const float*)d_in[2];
  const float* b1   = (const float*)d_in[3];
  const float* wih2 = (const float*)d_in[4];
  const float* whh2 = (const float*)d_in[5];
  const float* b2   = (const float*)d_in[6];
  const float* wih3 = (const float*)d_in[7];
  const float* whh3 = (const float*)d_in[8];
  const float* b3   = (const float*)d_in[9];
  const float* wfc  = (const float*)d_in[10];
  const float* bfc  = (const float*)d_in[11];
  float* out = (float*)d_out;

  lstm_fused<<<dim3(Bn / 16), dim3(768), 0, stream>>>(
      x, wih1, whh1, b1, wih2, whh2, b2, wih3, whh3, b3, wfc, bfc, out);
}